// Round 27
// baseline (165.746 us; speedup 1.0000x reference)
//
#include <hip/hip_runtime.h>
#include <math.h>

namespace {

constexpr int B_ = 4, N_ = 4, C_ = 64, H_ = 128, W_ = 128;
constexpr int HW_ = H_ * W_;
constexpr int CPB = 4;               // channels per barrier window
constexpr int NWIN = C_ / CPB;       // 16 windows per pass

// out[:, 4] = ref
__global__ __launch_bounds__(256) void copyref_kernel(const float* __restrict__ ref,
                                                      float* __restrict__ out) {
    int t = blockIdx.x * 256 + threadIdx.x;      // one float4 per thread
    int f = t * 4;
    int b = f / (C_ * HW_);
    int within = f - b * (C_ * HW_);
    float4 v = *reinterpret_cast<const float4*>(ref + (size_t)b * C_ * HW_ + within);
    *reinterpret_cast<float4*>(out + (size_t)(b * 5 + N_) * C_ * HW_ + within) = v;
}

// MERGED-i kernel: one block computes ALL FOUR output images for its 2 rows.
// Cross-round model: every adequately-occupied variant services logical
// (cache-level) traffic at ~7 TB/s -> we are L2/L3-BW-bound, and the only
// lever is logical traffic. Handling all 4 i's per block removes the
// q-streams entirely (sibling centers are already staged): 486 -> 285 MB
// (0.59x). Grid = B*(H/2) = 256 blocks = 1 block/CU = 1 wave/SIMD -- fine
// when BW-bound IF outstanding-load depth is kept high: CPB=4 staging = 36
// independent loads in flight per thread (~37 KB/CU > Little's-law ~17 KB).
// At 1 block/CU the VGPR budget is ~256, so the ~140-reg working set fits
// without spill (precedent: r24 ran 132 VGPR spill-free).
__global__ __launch_bounds__(256) void localcorr_kernel(const float* __restrict__ nbrs,
                                                        const float* __restrict__ ref,
                                                        float* __restrict__ out) {
    __shared__ float s_win[2][CPB][4][4][128];   // 64 KB: [buf][u][img][staged row][x]
    __shared__ float s_nrm[4][4][128];           // 8 KB: [img][staged row][x]

    const int blk = blockIdx.x;          // 0..255
    const int ypair = blk & 63;
    const int b = blk >> 6;
    const int t = (int)threadIdx.x;
    const int x = t & 127;
    const int ry = t >> 7;               // 0/1, wave-uniform
    const int y0 = ypair * 2;
    const int y = y0 + ry;

    // reflect-pad (np 'reflect', pad=1)
    const int xm = (x == 0) ? 1 : x - 1;
    const int xp = (x == W_ - 1) ? W_ - 2 : x + 1;
    const int gyA = (y0 == 0) ? 1 : y0 - 1;
    const int gyC = y0 + 1;
    const int gyD = (y0 + 2 == H_) ? H_ - 2 : y0 + 2;
    const int myRowA = (ry == 0) ? gyA : gyC;   // staged row 2ry
    const int myRowB = (ry == 0) ? y0 : gyD;    // staged row 2ry+1

    const float* __restrict__ nbq[4];
#pragma unroll
    for (int j = 0; j < 4; ++j) nbq[j] = nbrs + (size_t)(b * N_ + j) * C_ * HW_;
    const float* __restrict__ rp = ref + (size_t)b * C_ * HW_;
    const int offA = myRowA * W_ + x;
    const int offB = myRowB * W_ + x;
    const int offR = y * W_ + x;

    float dot[4][9];
#pragma unroll
    for (int j = 0; j < 4; ++j)
#pragma unroll
        for (int k = 0; k < 9; ++k) dot[j][k] = 0.f;
    float nA[4], nB[4];
#pragma unroll
    for (int j = 0; j < 4; ++j) { nA[j] = 0.f; nB[j] = 0.f; }
    float r2 = 0.f;

    // ---- pass 1: dots (all 4 images) + norms + ref2 ----
    float c0[CPB][4], c1[CPB][4], crf[CPB];
    float n0[CPB][4], n1[CPB][4], nrf[CPB];
#pragma unroll
    for (int u = 0; u < CPB; ++u) {
        const size_t co = (size_t)u * HW_;
#pragma unroll
        for (int j = 0; j < 4; ++j) {
            c0[u][j] = nbq[j][co + offA];
            c1[u][j] = nbq[j][co + offB];
        }
        crf[u] = rp[co + offR];
    }
#pragma unroll 1
    for (int w = 0; w < NWIN; ++w) {
        const int buf = w & 1;
#pragma unroll
        for (int u = 0; u < CPB; ++u)
#pragma unroll
            for (int j = 0; j < 4; ++j) {
                s_win[buf][u][j][2 * ry + 0][x] = c0[u][j];
                s_win[buf][u][j][2 * ry + 1][x] = c1[u][j];
            }
        __syncthreads();
        if (w + 1 < NWIN) {              // issue next batch AFTER barrier
#pragma unroll
            for (int u = 0; u < CPB; ++u) {
                const size_t co = (size_t)((w + 1) * CPB + u) * HW_;
#pragma unroll
                for (int j = 0; j < 4; ++j) {
                    n0[u][j] = nbq[j][co + offA];
                    n1[u][j] = nbq[j][co + offB];
                }
                nrf[u] = rp[co + offR];
            }
        }
#pragma unroll
        for (int u = 0; u < CPB; ++u) {
            const float rf = crf[u];
            r2 += rf * rf;
#pragma unroll
            for (int j = 0; j < 4; ++j) {
                const float* sc = &s_win[buf][u][j][0][0];
                const float w00 = sc[(ry + 0) * 128 + xm], w02 = sc[(ry + 0) * 128 + xp];
                const float w10 = sc[(ry + 1) * 128 + xm], w12 = sc[(ry + 1) * 128 + xp];
                const float w20 = sc[(ry + 2) * 128 + xm], w22 = sc[(ry + 2) * 128 + xp];
                float w01, w11, w21;
                if (ry == 0) { w01 = c0[u][j]; w11 = c1[u][j]; w21 = sc[2 * 128 + x]; }
                else         { w01 = sc[1 * 128 + x]; w11 = c0[u][j]; w21 = c1[u][j]; }
                nA[j] += c0[u][j] * c0[u][j];
                nB[j] += c1[u][j] * c1[u][j];
                dot[j][0] += rf * w00; dot[j][1] += rf * w01; dot[j][2] += rf * w02;
                dot[j][3] += rf * w10; dot[j][4] += rf * w11; dot[j][5] += rf * w12;
                dot[j][6] += rf * w20; dot[j][7] += rf * w21; dot[j][8] += rf * w22;
            }
        }
#pragma unroll
        for (int u = 0; u < CPB; ++u) {
#pragma unroll
            for (int j = 0; j < 4; ++j) { c0[u][j] = n0[u][j]; c1[u][j] = n1[u][j]; }
            crf[u] = nrf[u];
        }
    }

    // ---- share norms, softmax per image ----
#pragma unroll
    for (int j = 0; j < 4; ++j) {
        s_nrm[j][2 * ry + 0][x] = nA[j];
        s_nrm[j][2 * ry + 1][x] = nB[j];
    }
    __syncthreads();

    const float invr = rsqrtf(fmaxf(r2, 1e-24f));
    float wtp[4][9];
#pragma unroll
    for (int j = 0; j < 4; ++j) {
        float nk[9];
        nk[0] = s_nrm[j][ry + 0][xm]; nk[1] = s_nrm[j][ry + 0][x]; nk[2] = s_nrm[j][ry + 0][xp];
        nk[3] = s_nrm[j][ry + 1][xm]; nk[4] = s_nrm[j][ry + 1][x]; nk[5] = s_nrm[j][ry + 1][xp];
        nk[6] = s_nrm[j][ry + 2][xm]; nk[7] = s_nrm[j][ry + 2][x]; nk[8] = s_nrm[j][ry + 2][xp];
        float iv[9], d[9];
#pragma unroll
        for (int k = 0; k < 9; ++k) {
            iv[k] = rsqrtf(fmaxf(nk[k], 1e-24f));
            d[k] = dot[j][k] * invr * iv[k];
        }
        float mx = d[0];
#pragma unroll
        for (int k = 1; k < 9; ++k) mx = fmaxf(mx, d[k]);
        float ss = 0.f;
#pragma unroll
        for (int k = 0; k < 9; ++k) { d[k] = __expf(d[k] - mx); ss += d[k]; }
        const float is = 1.f / ss;
#pragma unroll
        for (int k = 0; k < 9; ++k) wtp[j][k] = d[k] * is * iv[k];
    }

    // ---- pass 2: aggregate all 4 images + mean from staged centers + store ----
    float* __restrict__ op[4];
#pragma unroll
    for (int j = 0; j < 4; ++j) op[j] = out + (size_t)(b * 5 + j) * C_ * HW_ + offR;

#pragma unroll
    for (int u = 0; u < CPB; ++u) {
        const size_t co = (size_t)u * HW_;
#pragma unroll
        for (int j = 0; j < 4; ++j) {
            c0[u][j] = nbq[j][co + offA];
            c1[u][j] = nbq[j][co + offB];
        }
    }
#pragma unroll 1
    for (int w = 0; w < NWIN; ++w) {
        const int buf = w & 1;
#pragma unroll
        for (int u = 0; u < CPB; ++u)
#pragma unroll
            for (int j = 0; j < 4; ++j) {
                s_win[buf][u][j][2 * ry + 0][x] = c0[u][j];
                s_win[buf][u][j][2 * ry + 1][x] = c1[u][j];
            }
        __syncthreads();
        if (w + 1 < NWIN) {
#pragma unroll
            for (int u = 0; u < CPB; ++u) {
                const size_t co = (size_t)((w + 1) * CPB + u) * HW_;
#pragma unroll
                for (int j = 0; j < 4; ++j) {
                    n0[u][j] = nbq[j][co + offA];
                    n1[u][j] = nbq[j][co + offB];
                }
            }
        }
#pragma unroll
        for (int u = 0; u < CPB; ++u) {
            float agg[4], ctr[4];
#pragma unroll
            for (int j = 0; j < 4; ++j) {
                const float* sc = &s_win[buf][u][j][0][0];
                const float w00 = sc[(ry + 0) * 128 + xm], w02 = sc[(ry + 0) * 128 + xp];
                const float w10 = sc[(ry + 1) * 128 + xm], w12 = sc[(ry + 1) * 128 + xp];
                const float w20 = sc[(ry + 2) * 128 + xm], w22 = sc[(ry + 2) * 128 + xp];
                float w01, w11, w21;
                if (ry == 0) { w01 = c0[u][j]; w11 = c1[u][j]; w21 = sc[2 * 128 + x]; }
                else         { w01 = sc[1 * 128 + x]; w11 = c0[u][j]; w21 = c1[u][j]; }
                agg[j] = wtp[j][0] * w00 + wtp[j][1] * w01 + wtp[j][2] * w02
                       + wtp[j][3] * w10 + wtp[j][4] * w11 + wtp[j][5] * w12
                       + wtp[j][6] * w20 + wtp[j][7] * w21 + wtp[j][8] * w22;
                ctr[j] = w11;
            }
            const float mu = 0.25f * (ctr[0] + ctr[1] + ctr[2] + ctr[3]);
            const size_t co = (size_t)(w * CPB + u) * HW_;
#pragma unroll
            for (int j = 0; j < 4; ++j) {
                const float dd = ctr[j] - mu;
                op[j][co] = agg[j] * __expf(-dd * dd);
            }
        }
#pragma unroll
        for (int u = 0; u < CPB; ++u)
#pragma unroll
            for (int j = 0; j < 4; ++j) { c0[u][j] = n0[u][j]; c1[u][j] = n1[u][j]; }
    }
}

}  // namespace

extern "C" void kernel_launch(void* const* d_in, const int* in_sizes, int n_in,
                              void* d_out, int out_size, void* d_ws, size_t ws_size,
                              hipStream_t stream) {
    const float* nbrs = (const float*)d_in[0];
    const float* ref = (const float*)d_in[1];
    float* out = (float*)d_out;

    // slot 4 = ref copy
    copyref_kernel<<<(B_ * C_ * HW_ / 4) / 256, 256, 0, stream>>>(ref, out);

    // main: B*(H/2) = 256 merged-i blocks of 256 threads
    localcorr_kernel<<<B_ * (H_ / 2), 256, 0, stream>>>(nbrs, ref, out);
}

// Round 28
// 80.572 us; speedup vs baseline: 2.0571x; 2.0571x over previous
//
#include <hip/hip_runtime.h>
#include <math.h>

namespace {

constexpr int B_ = 4, N_ = 4, C_ = 64, H_ = 128, W_ = 128;
constexpr int HW_ = H_ * W_;
constexpr int CPB = 4;               // channels per barrier window (per half)
constexpr int CHQ = 32;              // channels per q-half
constexpr int NWIN = CHQ / CPB;      // 8 windows per pass

// out[:, 4] = ref
__global__ __launch_bounds__(256) void copyref_kernel(const float* __restrict__ ref,
                                                      float* __restrict__ out) {
    int t = blockIdx.x * 256 + threadIdx.x;      // one float4 per thread
    int f = t * 4;
    int b = f / (C_ * HW_);
    int within = f - b * (C_ * HW_);
    float4 v = *reinterpret_cast<const float4*>(ref + (size_t)b * C_ * HW_ + within);
    *reinterpret_cast<float4*>(out + (size_t)(b * 5 + N_) * C_ * HW_ + within) = v;
}

// 2-WAY C-SPLIT, 512-thread blocks: r14's proven windowed-LDS structure at
// DOUBLE the wave count. q = tid>>8 handles 32 channels; per-thread state
// halves (dot[9] partial) -> targets the 64-VGPR / 8-waves-per-SIMD tier.
// 1024 blocks x 8 waves = 8192 waves = 32 waves/CU (100% nominal; r14 had 16).
// Windows/pass halve to 8 (19 barriers vs r14's 33). Cross-half dot/r2
// reduction goes through an LDS exchange that ALIASES the window buffer
// (dead between passes): LDS = 32KB windows + 2KB norms -> 4 blocks/CU.
__global__ __launch_bounds__(512) void localcorr_kernel(const float* __restrict__ nbrs,
                                                        const float* __restrict__ ref,
                                                        float* __restrict__ out) {
    __shared__ float s_mem[8192];      // 32 KB: windows [q][buf][u][4][128] / exchange union
    __shared__ float s_nrm[4][128];    // 2 KB: combined per-pixel sq-norms

    const int blk = blockIdx.x;        // 0..1023
    const int ypair = blk & 63;
    const int bi = blk >> 6;
    const int i = bi & 3;
    const int b = bi >> 2;
    const int t = (int)threadIdx.x;    // 0..511
    const int x = t & 127;
    const int ry = (t >> 7) & 1;       // row in pair
    const int q = t >> 8;              // channel half (wave-uniform)
    const int px = t & 255;            // ry*128 + x
    const int y0 = ypair * 2;
    const int y = y0 + ry;
    const int cb = q * CHQ;

    // reflect-pad (np 'reflect', pad=1)
    const int xm = (x == 0) ? 1 : x - 1;
    const int xp = (x == W_ - 1) ? W_ - 2 : x + 1;
    const int gyA = (y0 == 0) ? 1 : y0 - 1;
    const int gyC = y0 + 1;
    const int gyD = (y0 + 2 == H_) ? H_ - 2 : y0 + 2;
    const int myRowA = (ry == 0) ? gyA : gyC;   // staged row 2ry
    const int myRowB = (ry == 0) ? y0 : gyD;    // staged row 2ry+1

    const float* __restrict__ nb = nbrs + (size_t)(b * N_ + i) * C_ * HW_;
    const float* __restrict__ rp = ref + (size_t)b * C_ * HW_;
    const int offA = myRowA * W_ + x;
    const int offB = myRowB * W_ + x;
    const int offR = y * W_ + x;

    // window slot base helper: q*4096 + buf*2048 + u*512
    float dot[9];
#pragma unroll
    for (int k = 0; k < 9; ++k) dot[k] = 0.f;
    float nA = 0.f, nB = 0.f, r2 = 0.f;

    // ---- pass 1 over this half's 32 channels ----
    float co0[CPB], co1[CPB], crf[CPB];
    float no0[CPB], no1[CPB], nrf[CPB];
#pragma unroll
    for (int u = 0; u < CPB; ++u) {
        const size_t co = (size_t)(cb + u) * HW_;
        co0[u] = nb[co + offA]; co1[u] = nb[co + offB]; crf[u] = rp[co + offR];
    }
#pragma unroll 1
    for (int w = 0; w < NWIN; ++w) {
        float* wb = s_mem + q * 4096 + (w & 1) * 2048;
#pragma unroll
        for (int u = 0; u < CPB; ++u) {
            wb[u * 512 + (2 * ry + 0) * 128 + x] = co0[u];
            wb[u * 512 + (2 * ry + 1) * 128 + x] = co1[u];
        }
        if (w + 1 < NWIN) {
#pragma unroll
            for (int u = 0; u < CPB; ++u) {
                const size_t co = (size_t)(cb + (w + 1) * CPB + u) * HW_;
                no0[u] = nb[co + offA]; no1[u] = nb[co + offB]; nrf[u] = rp[co + offR];
            }
        }
        __syncthreads();
#pragma unroll
        for (int u = 0; u < CPB; ++u) {
            const float* sc = wb + u * 512;
            const float w00 = sc[(ry + 0) * 128 + xm], w02 = sc[(ry + 0) * 128 + xp];
            const float w10 = sc[(ry + 1) * 128 + xm], w12 = sc[(ry + 1) * 128 + xp];
            const float w20 = sc[(ry + 2) * 128 + xm], w22 = sc[(ry + 2) * 128 + xp];
            float w01, w11, w21;
            if (ry == 0) { w01 = co0[u]; w11 = co1[u]; w21 = sc[2 * 128 + x]; }
            else         { w01 = sc[1 * 128 + x]; w11 = co0[u]; w21 = co1[u]; }
            const float rf = crf[u];
            nA += co0[u] * co0[u]; nB += co1[u] * co1[u]; r2 += rf * rf;
            dot[0] += rf * w00; dot[1] += rf * w01; dot[2] += rf * w02;
            dot[3] += rf * w10; dot[4] += rf * w11; dot[5] += rf * w12;
            dot[6] += rf * w20; dot[7] += rf * w21; dot[8] += rf * w22;
        }
#pragma unroll
        for (int u = 0; u < CPB; ++u) { co0[u] = no0[u]; co1[u] = no1[u]; crf[u] = nrf[u]; }
    }

    // ---- cross-half exchange (aliases window buffer; dead between passes) ----
    __syncthreads();                   // all pass-1 window reads done
    // dx[q][k][px] at q*2304 + k*256 + px ; r2x[q][px] at 4608 + q*256 + px
#pragma unroll
    for (int k = 0; k < 9; ++k) s_mem[q * 2304 + k * 256 + px] = dot[k];
    s_mem[4608 + q * 256 + px] = r2;
    if (q == 0) {
        s_nrm[2 * ry + 0][x] = nA;
        s_nrm[2 * ry + 1][x] = nB;
    }
    __syncthreads();
    if (q == 1) {
        s_nrm[2 * ry + 0][x] += nA;
        s_nrm[2 * ry + 1][x] += nB;
    }
    const int oq = 1 - q;
#pragma unroll
    for (int k = 0; k < 9; ++k) dot[k] += s_mem[oq * 2304 + k * 256 + px];
    r2 += s_mem[4608 + oq * 256 + px];
    __syncthreads();                   // summed norms visible; dx reads done

    // ---- softmax over 9 neighbors (redundant in both halves) ----
    float nk[9];
    nk[0] = s_nrm[ry + 0][xm]; nk[1] = s_nrm[ry + 0][x]; nk[2] = s_nrm[ry + 0][xp];
    nk[3] = s_nrm[ry + 1][xm]; nk[4] = s_nrm[ry + 1][x]; nk[5] = s_nrm[ry + 1][xp];
    nk[6] = s_nrm[ry + 2][xm]; nk[7] = s_nrm[ry + 2][x]; nk[8] = s_nrm[ry + 2][xp];

    const float invr = rsqrtf(fmaxf(r2, 1e-24f));
    float inv[9], d[9];
#pragma unroll
    for (int k = 0; k < 9; ++k) {
        inv[k] = rsqrtf(fmaxf(nk[k], 1e-24f));
        d[k] = dot[k] * invr * inv[k];
    }
    float mx = d[0];
#pragma unroll
    for (int k = 1; k < 9; ++k) mx = fmaxf(mx, d[k]);
    float ssum = 0.f;
#pragma unroll
    for (int k = 0; k < 9; ++k) { d[k] = __expf(d[k] - mx); ssum += d[k]; }
    const float is = 1.f / ssum;
    float wtp[9];
#pragma unroll
    for (int k = 0; k < 9; ++k) wtp[k] = d[k] * is * inv[k];

    __syncthreads();                   // exchange region dead; pass 2 may restage

    // ---- pass 2 over this half's 32 channels ----
    const float* __restrict__ pm0 = nbrs + (size_t)(b * N_ + ((i + 1) & 3)) * C_ * HW_;
    const float* __restrict__ pm1 = nbrs + (size_t)(b * N_ + ((i + 2) & 3)) * C_ * HW_;
    const float* __restrict__ pm2 = nbrs + (size_t)(b * N_ + ((i + 3) & 3)) * C_ * HW_;
    float* __restrict__ op = out + (size_t)(b * 5 + i) * C_ * HW_ + offR;

    float q0c[CPB], q1c[CPB], q2c[CPB];
    float q0n[CPB], q1n[CPB], q2n[CPB];
#pragma unroll
    for (int u = 0; u < CPB; ++u) {
        const size_t co = (size_t)(cb + u) * HW_;
        co0[u] = nb[co + offA]; co1[u] = nb[co + offB];
        q0c[u] = pm0[co + offR]; q1c[u] = pm1[co + offR]; q2c[u] = pm2[co + offR];
    }
#pragma unroll 1
    for (int w = 0; w < NWIN; ++w) {
        float* wb = s_mem + q * 4096 + (w & 1) * 2048;
#pragma unroll
        for (int u = 0; u < CPB; ++u) {
            wb[u * 512 + (2 * ry + 0) * 128 + x] = co0[u];
            wb[u * 512 + (2 * ry + 1) * 128 + x] = co1[u];
        }
        if (w + 1 < NWIN) {
#pragma unroll
            for (int u = 0; u < CPB; ++u) {
                const size_t co = (size_t)(cb + (w + 1) * CPB + u) * HW_;
                no0[u] = nb[co + offA]; no1[u] = nb[co + offB];
                q0n[u] = pm0[co + offR]; q1n[u] = pm1[co + offR]; q2n[u] = pm2[co + offR];
            }
        }
        __syncthreads();
#pragma unroll
        for (int u = 0; u < CPB; ++u) {
            const float* sc = wb + u * 512;
            const float w00 = sc[(ry + 0) * 128 + xm], w02 = sc[(ry + 0) * 128 + xp];
            const float w10 = sc[(ry + 1) * 128 + xm], w12 = sc[(ry + 1) * 128 + xp];
            const float w20 = sc[(ry + 2) * 128 + xm], w22 = sc[(ry + 2) * 128 + xp];
            float w01, w11, w21;
            if (ry == 0) { w01 = co0[u]; w11 = co1[u]; w21 = sc[2 * 128 + x]; }
            else         { w01 = sc[1 * 128 + x]; w11 = co0[u]; w21 = co1[u]; }
            const float agg = wtp[0] * w00 + wtp[1] * w01 + wtp[2] * w02
                            + wtp[3] * w10 + wtp[4] * w11 + wtp[5] * w12
                            + wtp[6] * w20 + wtp[7] * w21 + wtp[8] * w22;
            const float ctr = w11;
            const float dd = ctr - 0.25f * (ctr + q0c[u] + q1c[u] + q2c[u]);
            op[(size_t)(cb + w * CPB + u) * HW_] = agg * __expf(-dd * dd);
        }
#pragma unroll
        for (int u = 0; u < CPB; ++u) {
            co0[u] = no0[u]; co1[u] = no1[u];
            q0c[u] = q0n[u]; q1c[u] = q1n[u]; q2c[u] = q2n[u];
        }
    }
}

}  // namespace

extern "C" void kernel_launch(void* const* d_in, const int* in_sizes, int n_in,
                              void* d_out, int out_size, void* d_ws, size_t ws_size,
                              hipStream_t stream) {
    const float* nbrs = (const float*)d_in[0];
    const float* ref = (const float*)d_in[1];
    float* out = (float*)d_out;

    // slot 4 = ref copy
    copyref_kernel<<<(B_ * C_ * HW_ / 4) / 256, 256, 0, stream>>>(ref, out);

    // main: B*N*(H/2) = 1024 blocks of 512 threads (2-way C-split)
    localcorr_kernel<<<B_ * N_ * (H_ / 2), 512, 0, stream>>>(nbrs, ref, out);
}